// Round 14
// baseline (137.651 us; speedup 1.0000x reference)
//
#include <hip/hip_runtime.h>
#include <math.h>

#define NB 32
#define NH 256
#define NLC 1024
#define NLQ 256
#define NEGV (-1e30f)
#define TCH 8      // column-stats l-chunks (each 128 rows, = sgemm l-tile)
#define KSPLIT 4   // tgemm split-K factor

typedef short short8 __attribute__((ext_vector_type(8)));
typedef float f32x4 __attribute__((ext_vector_type(4)));

__device__ inline short bf16_of(float f) {
  union { float f; unsigned u; } v;
  v.f = f;
  unsigned r = (v.u + 0x7fffu + ((v.u >> 16) & 1u)) >> 16;
  return (short)r;
}
__device__ inline float f_of(short s) {
  union { unsigned u; float f; } v;
  v.u = ((unsigned)(unsigned short)s) << 16;
  return v.f;
}
__device__ inline short8 cvt8(float4 a, float4 b) {
  short8 o;
  o[0] = bf16_of(a.x); o[1] = bf16_of(a.y); o[2] = bf16_of(a.z); o[3] = bf16_of(a.w);
  o[4] = bf16_of(b.x); o[5] = bf16_of(b.y); o[6] = bf16_of(b.z); o[7] = bf16_of(b.w);
  return o;
}

// XCD-aware bijective block swizzle (T1): consecutive logical tiles land on
// the same XCD's L2 so operand-sharing neighbor blocks hit instead of miss.
// Requires nwg % 8 == 0 (all our GEMM grids are).
#define XCD_SWZ(GX, GY, GZ, bx, by, bz)                                 \
  int bx, by, bz;                                                       \
  {                                                                     \
    int _lin = blockIdx.x + (GX) * (blockIdx.y + (GY) * blockIdx.z);    \
    const int _nwg = (GX) * (GY) * (GZ);                                \
    _lin = (_lin & 7) * (_nwg >> 3) + (_lin >> 3);                      \
    bx = _lin % (GX);                                                   \
    by = (_lin / (GX)) % (GY);                                          \
    bz = _lin / ((GX) * (GY));                                          \
  }

// ---- swizzled 128x32 bf16 LDS tile helpers (row = 64B, slot ^= (row>>1)&3) ----
__device__ inline void lds_w8(short* lds, int r, int c, short8 v) {
  int byteoff = (r << 6) + (((c ^ ((r >> 1) & 3)) & 3) << 4);
  *(short8*)((char*)lds + byteoff) = v;
}
__device__ inline short8 lds_r8(const short* lds, int R, int g) {
  int byteoff = (R << 6) + (((g ^ ((R >> 1) & 3)) & 3) << 4);
  return *(const short8*)((const char*)lds + byteoff);
}
// global_load_lds staging of a 128x32 bf16 tile from K-minor src (ld elements).
// Source group pre-permuted per-lane so linear LDS bytes match swizzled reads.
__device__ inline void stage_g(const short* src, int ld, short* lds, int t) {
  int L = t & 63, w = t >> 6;
  int cp = (L & 3) ^ ((L >> 3) & 3);
#pragma unroll
  for (int i = 0; i < 2; ++i) {
    int seg = w + i * 4;
    const short* g = src + (size_t)(seg * 16 + (L >> 2)) * ld + cp * 8;
    __builtin_amdgcn_global_load_lds(
        (const __attribute__((address_space(1))) unsigned int*)g,
        (__attribute__((address_space(3))) unsigned int*)(lds + seg * 512), 16,
        0, 0);
  }
}

#define GEMM_IDS                                       \
  int t = threadIdx.x, lane = t & 63, w = t >> 6;      \
  int ln = lane & 15, g = lane >> 4;                   \
  int wr = (w >> 1) << 6, wc = (w & 1) << 6;           \
  (void)wr; (void)wc;

#define MFMA_STEP(AS, BS)                                                      \
  {                                                                            \
    short8 af[4], bfr[4];                                                      \
    _Pragma("unroll") for (int mi = 0; mi < 4; ++mi) af[mi] =                  \
        lds_r8(AS, wr + mi * 16 + ln, g);                                      \
    _Pragma("unroll") for (int ni = 0; ni < 4; ++ni) bfr[ni] =                 \
        lds_r8(BS, wc + ni * 16 + ln, g);                                      \
    _Pragma("unroll") for (int mi = 0; mi < 4; ++mi)                           \
        _Pragma("unroll") for (int ni = 0; ni < 4; ++ni) acc[mi][ni] =         \
            __builtin_amdgcn_mfma_f32_16x16x32_bf16(af[mi], bfr[ni],           \
                                                    acc[mi][ni], 0, 0, 0);     \
  }

// -- prep: Ct_lh[l][h] = bf16(C[h][l]); Cb_hl[h][l] = bf16(C); s1 partials --
__global__ __launch_bounds__(256) void k_prep_c(const float* __restrict__ C,
                                                const float* __restrict__ w,
                                                short* __restrict__ Ct_lh,
                                                short* __restrict__ Cb_hl,
                                                float* __restrict__ s1p) {
  __shared__ float Ts[64][65];
  __shared__ float red[4][64];
  int b = blockIdx.z, h0 = blockIdx.y << 6, l0 = blockIdx.x << 6;
  int t = threadIdx.x;
  int hr = t >> 4, lc = (t & 15) << 2;
  const float* Cb = C + ((size_t)b * NH + h0) * NLC + l0;
#pragma unroll
  for (int i = 0; i < 4; ++i) {
    int h = hr + i * 16;
    float4 v = *(const float4*)&Cb[(size_t)h * NLC + lc];
    short4 cb;
    cb.x = bf16_of(v.x); cb.y = bf16_of(v.y);
    cb.z = bf16_of(v.z); cb.w = bf16_of(v.w);
    *(short4*)&Cb_hl[((size_t)b * NH + h0 + h) * NLC + l0 + lc] = cb;
    Ts[h][lc + 0] = v.x;
    Ts[h][lc + 1] = v.y;
    Ts[h][lc + 2] = v.z;
    Ts[h][lc + 3] = v.w;
  }
  __syncthreads();
  int lr = t >> 2, hc = (t & 3) << 4;
  short* dst = &Ct_lh[((size_t)b * NLC + l0 + lr) * NH + h0 + hc];
  short8 o0, o1;
#pragma unroll
  for (int j = 0; j < 8; ++j) o0[j] = bf16_of(Ts[hc + j][lr]);
#pragma unroll
  for (int j = 0; j < 8; ++j) o1[j] = bf16_of(Ts[hc + 8 + j][lr]);
  *(short8*)dst = o0;
  *(short8*)(dst + 8) = o1;
  // s1 partial: sum over this block's 64 h of C[h][l]*w1[h]
  int q = t >> 6, lq = t & 63;
  float a = 0.f;
#pragma unroll
  for (int j = 0; j < 16; ++j) a += Ts[(q << 4) + j][lq] * w[h0 + (q << 4) + j];
  red[q][lq] = a;
  __syncthreads();
  if (q == 0)
    s1p[((size_t)blockIdx.y * NB + b) * NLC + l0 + lq] =
        red[0][lq] + red[1][lq] + red[2][lq] + red[3][lq];
}

// ---- prep: Qtw3[m][h]=bf16(Q[h][m]*w3[h]); Qb_hm=bf16(Q); s2 partials;
// also folds the W_res f32->bf16 copy (512 elems per block). ----
__global__ __launch_bounds__(256) void k_prep_q(const float* __restrict__ Q,
                                                const float* __restrict__ w,
                                                const float* __restrict__ Wf,
                                                short* __restrict__ Qtw3,
                                                short* __restrict__ Qb_hm,
                                                short* __restrict__ Wb,
                                                float* __restrict__ s2p) {
  __shared__ float Ts[64][65];
  __shared__ float red[4][64];
  int b = blockIdx.z, h0 = blockIdx.y << 6, m0 = blockIdx.x << 6;
  int t = threadIdx.x;
  // W fold: linear block id in [0,512) covers 262144 elems, 2 per thread.
  {
    size_t wi =
        ((size_t)((blockIdx.z * 4 + blockIdx.y) * 4 + blockIdx.x) * 256 + t) *
        2;
    float2 wv = *(const float2*)&Wf[wi];
    short2 ws2;
    ws2.x = bf16_of(wv.x);
    ws2.y = bf16_of(wv.y);
    *(short2*)&Wb[wi] = ws2;
  }
  int hr = t >> 4, mc = (t & 15) << 2;
  const float* w3 = w + 2 * NH;
  const float* Qb = Q + ((size_t)b * NH + h0) * NLQ + m0;
#pragma unroll
  for (int i = 0; i < 4; ++i) {
    int h = hr + i * 16;
    float4 v = *(const float4*)&Qb[(size_t)h * NLQ + mc];
    short4 qb;
    qb.x = bf16_of(v.x); qb.y = bf16_of(v.y);
    qb.z = bf16_of(v.z); qb.w = bf16_of(v.w);
    *(short4*)&Qb_hm[((size_t)b * NH + h0 + h) * NLQ + m0 + mc] = qb;
    Ts[h][mc + 0] = v.x;
    Ts[h][mc + 1] = v.y;
    Ts[h][mc + 2] = v.z;
    Ts[h][mc + 3] = v.w;
  }
  __syncthreads();
  int mr = t >> 2, hc = (t & 3) << 4;
  short* dst = &Qtw3[((size_t)b * NLQ + m0 + mr) * NH + h0 + hc];
  short8 o0, o1;
#pragma unroll
  for (int j = 0; j < 8; ++j)
    o0[j] = bf16_of(Ts[hc + j][mr] * w3[h0 + hc + j]);
#pragma unroll
  for (int j = 0; j < 8; ++j)
    o1[j] = bf16_of(Ts[hc + 8 + j][mr] * w3[h0 + hc + 8 + j]);
  *(short8*)dst = o0;
  *(short8*)(dst + 8) = o1;
  // s2 partial over this block's 64 h, straight from the raw-Q LDS tile
  int q = t >> 6, mq = t & 63;
  const float* w2 = w + NH;
  float a = 0.f;
#pragma unroll
  for (int j = 0; j < 16; ++j)
    a += Ts[(q << 4) + j][mq] * w2[h0 + (q << 4) + j];
  red[q][mq] = a;
  __syncthreads();
  if (q == 0)
    s2p[((size_t)blockIdx.y * NB + b) * NLQ + m0 + mq] =
        red[0][mq] + red[1][mq] + red[2][mq] + red[3][mq];
}

// ------- S = Ct_lh @ Qtw3^T + s1 + s2  (M=l, N=m, K=h); 2-phase dbuf.
// Epilogue reduces s1p/s2p partials in-register and emits column-softmax
// partials straight from registers -> pmax/psum chunk = by.
__global__ __launch_bounds__(256) void k_sgemm(
    const short* __restrict__ Ct_lh, const short* __restrict__ Qtw3,
    const float* __restrict__ s1p, const float* __restrict__ s2p,
    const int* __restrict__ cmask, float* __restrict__ S,
    float* __restrict__ pmax, float* __restrict__ psum) {
  __shared__ short As[2][4096], Bs[2][4096];
  __shared__ float cmsh[128];
  __shared__ float sredm[4][4][16], sreds[4][4][16];
  XCD_SWZ(NLQ / 128, NLC / 128, NB, bx, by, bz)
  int b = bz, l0 = by << 7, m0 = bx << 7;
  GEMM_IDS
  const short* Ag = Ct_lh + ((size_t)b * NLC + l0) * NH;
  const short* Bg = Qtw3 + ((size_t)b * NLQ + m0) * NH;
  f32x4 acc[4][4] = {};
  stage_g(Ag, NH, As[0], t);
  stage_g(Bg, NH, Bs[0], t);
  __syncthreads();
  int cur = 0;
  for (int kn = 32; kn <= NH; kn += 32) {
    if (kn < NH) {
      stage_g(Ag + kn, NH, As[cur ^ 1], t);
      stage_g(Bg + kn, NH, Bs[cur ^ 1], t);
    }
    MFMA_STEP(As[cur], Bs[cur])
    __syncthreads();
    cur ^= 1;
  }
  // ---- epilogue: S write + column partials from registers ----
  if (t < 128) cmsh[t] = cmask[b * NLC + l0 + t] ? 0.f : NEGV;
  __syncthreads();
  const int N1 = NB * NLC, N2 = NB * NLQ;
  float s1r[16], ncr[16];
#pragma unroll
  for (int mi = 0; mi < 4; ++mi)
#pragma unroll
    for (int r = 0; r < 4; ++r) {
      int lloc = wr + mi * 16 + g * 4 + r;
      int gl = b * NLC + l0 + lloc;
      s1r[mi * 4 + r] =
          s1p[gl] + s1p[N1 + gl] + s1p[2 * N1 + gl] + s1p[3 * N1 + gl];
      ncr[mi * 4 + r] = cmsh[lloc];
    }
  float s2v[4], mxc[4], smc[4];
#pragma unroll
  for (int ni = 0; ni < 4; ++ni) {
    int gm = b * NLQ + m0 + wc + ni * 16 + ln;
    s2v[ni] = s2p[gm] + s2p[N2 + gm] + s2p[2 * N2 + gm] + s2p[3 * N2 + gm];
    mxc[ni] = -INFINITY;
    smc[ni] = 0.f;
  }
#pragma unroll
  for (int ni = 0; ni < 4; ++ni)
#pragma unroll
    for (int mi = 0; mi < 4; ++mi)
#pragma unroll
      for (int r = 0; r < 4; ++r)
        mxc[ni] = fmaxf(mxc[ni],
                        acc[mi][ni][r] + s1r[mi * 4 + r] + s2v[ni] +
                            ncr[mi * 4 + r]);
#pragma unroll
  for (int ni = 0; ni < 4; ++ni) {
    int m = m0 + wc + ni * 16 + ln;
#pragma unroll
    for (int mi = 0; mi < 4; ++mi)
#pragma unroll
      for (int r = 0; r < 4; ++r) {
        int l = l0 + wr + mi * 16 + g * 4 + r;
        float sv = acc[mi][ni][r] + s1r[mi * 4 + r] + s2v[ni];
        S[((size_t)b * NLC + l) * NLQ + m] = sv;
        smc[ni] += expf(sv + ncr[mi * 4 + r] - mxc[ni]);
      }
  }
  // butterfly across the 4 lane-groups (same ln, different g)
#pragma unroll
  for (int off = 16; off <= 32; off <<= 1)
#pragma unroll
    for (int ni = 0; ni < 4; ++ni) {
      float m2 = __shfl_xor(mxc[ni], off);
      float s2x = __shfl_xor(smc[ni], off);
      float nm = fmaxf(mxc[ni], m2);
      smc[ni] = smc[ni] * expf(mxc[ni] - nm) + s2x * expf(m2 - nm);
      mxc[ni] = nm;
    }
  if (lane < 16) {
#pragma unroll
    for (int ni = 0; ni < 4; ++ni) {
      sredm[w][ni][lane] = mxc[ni];
      sreds[w][ni][lane] = smc[ni];
    }
  }
  __syncthreads();
  if (t < 128) {
    int wcsel = t >> 6, nii = (t >> 4) & 3, lnn = t & 15;
    float mA = sredm[wcsel][nii][lnn], sA = sreds[wcsel][nii][lnn];
    float mB = sredm[wcsel + 2][nii][lnn], sB = sreds[wcsel + 2][nii][lnn];
    float nm = fmaxf(mA, mB);
    float sm = sA * expf(mA - nm) + sB * expf(mB - nm);
    int m = m0 + (wcsel << 6) + nii * 16 + lnn;
    size_t base = ((size_t)b * NLQ + m) * TCH + by;
    pmax[base] = nm;
    psum[base] = sm;
  }
}

// combine TCH partials per column -> cmax, cinv. One thread per column.
__global__ __launch_bounds__(256) void k_colfin(const float* __restrict__ pmax,
                                                const float* __restrict__ psum,
                                                float* __restrict__ cmax,
                                                float* __restrict__ cinv) {
  int m = blockIdx.x * 256 + threadIdx.x;  // [0, NB*NLQ)
  const float* pm = pmax + (size_t)m * TCH;
  const float* ps = psum + (size_t)m * TCH;
  float mx = pm[0], sm = ps[0];
#pragma unroll
  for (int c = 1; c < TCH; ++c) {
    float m2 = pm[c], s2 = ps[c];
    float nm = fmaxf(mx, m2);
    sm = sm * expf(mx - nm) + s2 * expf(m2 - nm);
    mx = nm;
  }
  cmax[m] = mx;
  cinv[m] = 1.0f / sm;
}

// ---- row softmax IN PLACE (bf16 P_row in bytes 0..511 of each 1KB S row)
// + column softmax written TRANSPOSED to PcolT[b][m][l] (bf16, coalesced)
// via an LDS transpose tile. Block = 64 l-rows x full m.
__global__ __launch_bounds__(256) void k_colsoft(
    float* __restrict__ S, const int* __restrict__ qmask,
    const int* __restrict__ cmask, const float* __restrict__ cmax,
    const float* __restrict__ cinv, short* __restrict__ PcolT) {
  __shared__ short PT[64][258];  // odd dword stride: conflict-free columns
  int b = blockIdx.z, l0 = blockIdx.x << 6;
  int t = threadIdx.x, lane = t & 63, wv = t >> 6;
  int m4 = lane << 2;
  const int* qm = qmask + b * NLQ;
  int4 q = *(const int4*)&qm[m4];
  float nq0 = q.x ? 0.f : NEGV, nq1 = q.y ? 0.f : NEGV;
  float nq2 = q.z ? 0.f : NEGV, nq3 = q.w ? 0.f : NEGV;
  float4 cm4 = *(const float4*)&cmax[(b << 8) + m4];
  float4 ci4 = *(const float4*)&cinv[(b << 8) + m4];
  for (int i = 0; i < 16; ++i) {
    int lloc = wv * 16 + i;
    int idx = b * NLC + l0 + lloc;
    float* row = S + (size_t)idx * NLQ;
    float4 v = *(const float4*)&row[m4];
    float x0 = v.x + nq0, x1 = v.y + nq1, x2 = v.z + nq2, x3 = v.w + nq3;
    float mx = fmaxf(fmaxf(x0, x1), fmaxf(x2, x3));
#pragma unroll
    for (int off = 32; off > 0; off >>= 1) mx = fmaxf(mx, __shfl_xor(mx, off));
    float p0 = expf(x0 - mx), p1 = expf(x1 - mx);
    float p2 = expf(x2 - mx), p3 = expf(x3 - mx);
    float sm = p0 + p1 + p2 + p3;
#pragma unroll
    for (int off = 32; off > 0; off >>= 1) sm += __shfl_xor(sm, off);
    float iv = 1.0f / sm;
    short4 o;
    o.x = bf16_of(p0 * iv);
    o.y = bf16_of(p1 * iv);
    o.z = bf16_of(p2 * iv);
    o.w = bf16_of(p3 * iv);
    *(short4*)((short*)row + m4) = o;
    float cmf = cmask[idx] ? 1.f : 0.f;
    PT[lloc][m4 + 0] = bf16_of(expf(v.x - cm4.x) * ci4.x * cmf);
    PT[lloc][m4 + 1] = bf16_of(expf(v.y - cm4.y) * ci4.y * cmf);
    PT[lloc][m4 + 2] = bf16_of(expf(v.z - cm4.z) * ci4.z * cmf);
    PT[lloc][m4 + 3] = bf16_of(expf(v.w - cm4.w) * ci4.w * cmf);
  }
  __syncthreads();
  // transposed store: thread t owns column m=t -> 128B contiguous global.
  short* dst = PcolT + ((size_t)b * NLQ + t) * NLC + l0;
#pragma unroll
  for (int j = 0; j < 8; ++j) {
    short8 o8;
#pragma unroll
    for (int k = 0; k < 8; ++k) o8[k] = PT[j * 8 + k][t];
    *(short8*)&dst[j * 8] = o8;
  }
}

// ------ Tpb[ks][b][h][m] = sum_{l in chunk ks} C[h][l] * PcolT[m][l] ------
// split-K partials (bf16); M=h, N=m, K=l chunk of 256. Both operands DMA;
// 2-phase dbuf.
__global__ __launch_bounds__(256) void k_tgemm(const short* __restrict__ Cb_hl,
                                               const short* __restrict__ PcolT,
                                               short* __restrict__ Tpb) {
  __shared__ short As[2][4096], Bs[2][4096];
  XCD_SWZ(4, KSPLIT, NB, bx, by, bz)
  int b = bz;
  int ks = by;
  int h0 = (bx & 1) << 7;
  int m0 = (bx >> 1) << 7;
  GEMM_IDS
  const short* Ag = Cb_hl + ((size_t)b * NH + h0) * NLC;
  const short* Bg = PcolT + ((size_t)b * NLQ + m0) * NLC;
  f32x4 acc[4][4] = {};
  int kbeg = ks * (NLC / KSPLIT), kend = kbeg + NLC / KSPLIT;
  stage_g(Ag + kbeg, NLC, As[0], t);
  stage_g(Bg + kbeg, NLC, Bs[0], t);
  __syncthreads();
  int cur = 0;
  for (int kn = kbeg + 32; kn <= kend; kn += 32) {
    if (kn < kend) {
      stage_g(Ag + kn, NLC, As[cur ^ 1], t);
      stage_g(Bg + kn, NLC, Bs[cur ^ 1], t);
    }
    MFMA_STEP(As[cur], Bs[cur])
    __syncthreads();
    cur ^= 1;
  }
  short* dst = Tpb + ((size_t)ks * NB + b) * NH * NLQ;
#pragma unroll
  for (int mi = 0; mi < 4; ++mi)
#pragma unroll
    for (int ni = 0; ni < 4; ++ni)
#pragma unroll
      for (int r = 0; r < 4; ++r) {
        int h = h0 + wr + mi * 16 + g * 4 + r;
        int m = m0 + wc + ni * 16 + ln;
        dst[(size_t)h * NLQ + m] = bf16_of(acc[mi][ni][r]);
      }
}

// reduce KSPLIT bf16 partials -> bf16 Tt[b][h][m], 8 elems/thread
__global__ __launch_bounds__(256) void k_tfin(const short* __restrict__ Tpb,
                                              short* __restrict__ Tt) {
  size_t i = ((size_t)blockIdx.x * 256 + threadIdx.x) * 8;
  const size_t stride = (size_t)NB * NH * NLQ;
  short8 x0 = *(const short8*)&Tpb[i];
  short8 x1 = *(const short8*)&Tpb[i + stride];
  short8 x2 = *(const short8*)&Tpb[i + 2 * stride];
  short8 x3 = *(const short8*)&Tpb[i + 3 * stride];
  short8 o;
#pragma unroll
  for (int j = 0; j < 8; ++j)
    o[j] = bf16_of(f_of(x0[j]) + f_of(x1[j]) + f_of(x2[j]) + f_of(x3[j]));
  *(short8*)&Tt[i] = o;
}

// ---- [A | Ct*Bv][l][h] = f(sum_m P_row[l][m] * X[h][m]); 2-phase dbuf.
// nb<2 epilogue ALSO writes CtA_lh = Ct*A so k_out stages it via pure DMA.
__global__ __launch_bounds__(256) void k_abgemm(
    const short* __restrict__ Prow, const short* __restrict__ Qb_hm,
    const short* __restrict__ Tt, const short* __restrict__ Ct_lh,
    short* __restrict__ A_lh, short* __restrict__ CtA_lh,
    short* __restrict__ CtBv_lh) {
  __shared__ short As[2][4096], Bs[2][4096];
  XCD_SWZ(4, NLC / 128, NB, bx, by, bz)
  int b = bz, l0 = by << 7, nb = bx;
  GEMM_IDS
  const short* Ag = Prow + ((size_t)b * NLC + l0) * 512;
  const short* Bbase = (nb < 2)
                           ? Qb_hm + ((size_t)b * NH + nb * 128) * NLQ
                           : Tt + ((size_t)b * NH + (nb - 2) * 128) * NLQ;
  f32x4 acc[4][4] = {};
  stage_g(Ag, 512, As[0], t);
  stage_g(Bbase, NLQ, Bs[0], t);
  __syncthreads();
  int cur = 0;
  for (int kn = 32; kn <= NLQ; kn += 32) {
    if (kn < NLQ) {
      stage_g(Ag + kn, 512, As[cur ^ 1], t);
      stage_g(Bbase + kn, NLQ, Bs[cur ^ 1], t);
    }
    MFMA_STEP(As[cur], Bs[cur])
    __syncthreads();
    cur ^= 1;
  }
  int hbase = (nb & 1) << 7;
  if (nb < 2) {
#pragma unroll
    for (int mi = 0; mi < 4; ++mi)
#pragma unroll
      for (int ni = 0; ni < 4; ++ni)
#pragma unroll
        for (int r = 0; r < 4; ++r) {
          int l = l0 + wr + mi * 16 + g * 4 + r;
          int h = hbase + wc + ni * 16 + ln;
          size_t off = ((size_t)b * NLC + l) * NH + h;
          float a = acc[mi][ni][r];
          A_lh[off] = bf16_of(a);
          CtA_lh[off] = bf16_of(f_of(Ct_lh[off]) * a);
        }
  } else {
#pragma unroll
    for (int mi = 0; mi < 4; ++mi)
#pragma unroll
      for (int ni = 0; ni < 4; ++ni)
#pragma unroll
        for (int r = 0; r < 4; ++r) {
          int l = l0 + wr + mi * 16 + g * 4 + r;
          int h = hbase + wc + ni * 16 + ln;
          size_t off = ((size_t)b * NLC + l) * NH + h;
          CtBv_lh[off] = bf16_of(f_of(Ct_lh[off]) * acc[mi][ni][r]);
        }
  }
}

// -------- out[h][l] = relu(b + sum_f W[h][f]*cat[l][f]); 2-phase dbuf --------
// cat regions along f: [Ct | A | Ct*A | Ct*Bv] -- ALL pure stage_g DMA.
__global__ __launch_bounds__(256) void k_out(
    const short* __restrict__ Wb, const short* __restrict__ Ct_lh,
    const short* __restrict__ A_lh, const short* __restrict__ CtA_lh,
    const short* __restrict__ CtBv_lh, const float* __restrict__ br,
    float* __restrict__ out) {
  __shared__ short As[2][4096], Bs[2][4096];
  XCD_SWZ(NLC / 128, NH / 128, NB, bx, by, bz)
  int b = bz, h0 = by << 7, l0 = bx << 7;
  GEMM_IDS
  const short* Wg = Wb + (size_t)h0 * (4 * NH);
  size_t boff = ((size_t)b * NLC + l0) * NH;
  f32x4 acc[4][4] = {};
  stage_g(Wg, 4 * NH, As[0], t);
  stage_g(Ct_lh + boff, NH, Bs[0], t);  // tile 0 is region 0 (Ct)
  __syncthreads();
  int cur = 0;
  for (int kn = 32; kn <= 4 * NH; kn += 32) {
    bool has = kn < 4 * NH;
    if (has) {
      stage_g(Wg + kn, 4 * NH, As[cur ^ 1], t);
      int regn = kn >> 8, kon = kn & 255;
      const short* base = (regn == 0) ? Ct_lh
                          : (regn == 1) ? A_lh
                          : (regn == 2) ? CtA_lh : CtBv_lh;
      stage_g(base + boff + kon, NH, Bs[cur ^ 1], t);
    }
    MFMA_STEP(As[cur], Bs[cur])
    __syncthreads();
    cur ^= 1;
  }
#pragma unroll
  for (int mi = 0; mi < 4; ++mi)
#pragma unroll
    for (int ni = 0; ni < 4; ++ni) {
      int h = h0 + wr + mi * 16 + g * 4;
      int l = l0 + wc + ni * 16 + ln;
#pragma unroll
      for (int r = 0; r < 4; ++r) {
        float bias = br[h + r];
        out[((size_t)b * NH + h + r) * NLC + l] =
            fmaxf(acc[mi][ni][r] + bias, 0.f);
      }
    }
}

extern "C" void kernel_launch(void* const* d_in, const int* in_sizes, int n_in,
                              void* d_out, int out_size, void* d_ws,
                              size_t ws_size, hipStream_t stream) {
  (void)in_sizes;
  (void)n_in;
  (void)out_size;
  (void)ws_size;
  const float* C = (const float*)d_in[0];
  const float* Q = (const float*)d_in[1];
  const int* cmask = (const int*)d_in[2];
  const int* qmask = (const int*)d_in[3];
  const float* w = (const float*)d_in[4];
  const float* W = (const float*)d_in[5];
  const float* br = (const float*)d_in[6];
  float* out = (float*)d_out;

  char* p = (char*)d_ws;
  float* S = (float*)p;       p += (size_t)NB * NLC * NLQ * 4;   // 33.6 MB
  short* Ct_lh = (short*)p;   p += (size_t)NB * NLC * NH * 2;    // 16.8 MB
  short* A_lh = (short*)p;    p += (size_t)NB * NLC * NH * 2;    // 16.8 MB
  short* CtBv_lh = (short*)p; p += (size_t)NB * NLC * NH * 2;    // 16.8 MB
  short* CtA_lh = (short*)p;  p += (size_t)NB * NLC * NH * 2;    // 16.8 MB
  short* Cb_hl = (short*)p;   p += (size_t)NB * NH * NLC * 2;    // 16.8 MB
  short* PcolT = (short*)p;   p += (size_t)NB * NLQ * NLC * 2;   // 16.8 MB
  short* Tt = (short*)p;      p += (size_t)NB * NH * NLQ * 2;    // 4.2 MB
  short* Qtw3 = (short*)p;    p += (size_t)NB * NLQ * NH * 2;    // 4.2 MB
  short* Qb_hm = (short*)p;   p += (size_t)NB * NH * NLQ * 2;    // 4.2 MB
  short* Wb = (short*)p;      p += (size_t)NH * 4 * NH * 2;      // 0.5 MB
  float* cmax = (float*)p;    p += (size_t)NB * NLQ * 4;
  float* cinv = (float*)p;    p += (size_t)NB * NLQ * 4;
  float* pmax = (float*)p;    p += (size_t)NB * NLQ * TCH * 4;
  float* psum = (float*)p;    p += (size_t)NB * NLQ * TCH * 4;
  float* s1p = (float*)p;     p += (size_t)4 * NB * NLC * 4;     // 0.5 MB
  float* s2p = (float*)p;     p += (size_t)4 * NB * NLQ * 4;     // 0.13 MB
  // tgemm split-K bf16 partials: reuse A_lh (16.8 MB, dead until abgemm).
  short* Tpb = A_lh;
  // in-place row softmax: bf16 P_row at bytes 0..511 of each 1KB S row.
  short* Prow = (short*)S;

  k_prep_c<<<dim3(NLC / 64, NH / 64, NB), dim3(256), 0, stream>>>(C, w, Ct_lh,
                                                                  Cb_hl, s1p);
  k_prep_q<<<dim3(NLQ / 64, NH / 64, NB), dim3(256), 0, stream>>>(
      Q, w, W, Qtw3, Qb_hm, Wb, s2p);
  k_sgemm<<<dim3(NLQ / 128, NLC / 128, NB), dim3(256), 0, stream>>>(
      Ct_lh, Qtw3, s1p, s2p, cmask, S, pmax, psum);
  k_colfin<<<dim3(NB * NLQ / 256), dim3(256), 0, stream>>>(pmax, psum, cmax,
                                                           cinv);
  k_colsoft<<<dim3(NLC / 64, 1, NB), dim3(256), 0, stream>>>(S, qmask, cmask,
                                                             cmax, cinv,
                                                             PcolT);
  k_tgemm<<<dim3(4, KSPLIT, NB), dim3(256), 0, stream>>>(Cb_hl, PcolT, Tpb);
  k_tfin<<<dim3(NB * NH * NLQ / 2048), dim3(256), 0, stream>>>(Tpb, Tt);
  k_abgemm<<<dim3(4, NLC / 128, NB), dim3(256), 0, stream>>>(
      Prow, Qb_hm, Tt, Ct_lh, A_lh, CtA_lh, CtBv_lh);
  k_out<<<dim3(NLC / 128, NH / 128, NB), dim3(256), 0, stream>>>(
      Wb, Ct_lh, A_lh, CtA_lh, CtBv_lh, br, out);
}

// Round 15
// 134.681 us; speedup vs baseline: 1.0221x; 1.0221x over previous
//
#include <hip/hip_runtime.h>
#include <math.h>

#define NB 32
#define NH 256
#define NLC 1024
#define NLQ 256
#define NEGV (-1e30f)
#define TCH 8      // column-stats l-chunks (each 128 rows, = sgemm l-tile)
#define KSPLIT 4   // tgemm split-K factor

typedef short short8 __attribute__((ext_vector_type(8)));
typedef float f32x4 __attribute__((ext_vector_type(4)));

__device__ inline short bf16_of(float f) {
  union { float f; unsigned u; } v;
  v.f = f;
  unsigned r = (v.u + 0x7fffu + ((v.u >> 16) & 1u)) >> 16;
  return (short)r;
}
__device__ inline float f_of(short s) {
  union { unsigned u; float f; } v;
  v.u = ((unsigned)(unsigned short)s) << 16;
  return v.f;
}
__device__ inline short8 cvt8(float4 a, float4 b) {
  short8 o;
  o[0] = bf16_of(a.x); o[1] = bf16_of(a.y); o[2] = bf16_of(a.z); o[3] = bf16_of(a.w);
  o[4] = bf16_of(b.x); o[5] = bf16_of(b.y); o[6] = bf16_of(b.z); o[7] = bf16_of(b.w);
  return o;
}

// XCD-aware bijective block swizzle (T1): consecutive logical tiles land on
// the same XCD's L2 so operand-sharing neighbor blocks hit instead of miss.
// Requires nwg % 8 == 0 (all our GEMM grids are).
#define XCD_SWZ(GX, GY, GZ, bx, by, bz)                                 \
  int bx, by, bz;                                                       \
  {                                                                     \
    int _lin = blockIdx.x + (GX) * (blockIdx.y + (GY) * blockIdx.z);    \
    const int _nwg = (GX) * (GY) * (GZ);                                \
    _lin = (_lin & 7) * (_nwg >> 3) + (_lin >> 3);                      \
    bx = _lin % (GX);                                                   \
    by = (_lin / (GX)) % (GY);                                          \
    bz = _lin / ((GX) * (GY));                                          \
  }

// ---- swizzled 128x32 bf16 LDS tile helpers (row = 64B, slot ^= (row>>1)&3) ----
__device__ inline void lds_w8(short* lds, int r, int c, short8 v) {
  int byteoff = (r << 6) + (((c ^ ((r >> 1) & 3)) & 3) << 4);
  *(short8*)((char*)lds + byteoff) = v;
}
__device__ inline short8 lds_r8(const short* lds, int R, int g) {
  int byteoff = (R << 6) + (((g ^ ((R >> 1) & 3)) & 3) << 4);
  return *(const short8*)((const char*)lds + byteoff);
}
// global_load_lds staging of a 128x32 bf16 tile from K-minor src (ld elements).
// Source group pre-permuted per-lane so linear LDS bytes match swizzled reads.
__device__ inline void stage_g(const short* src, int ld, short* lds, int t) {
  int L = t & 63, w = t >> 6;
  int cp = (L & 3) ^ ((L >> 3) & 3);
#pragma unroll
  for (int i = 0; i < 2; ++i) {
    int seg = w + i * 4;
    const short* g = src + (size_t)(seg * 16 + (L >> 2)) * ld + cp * 8;
    __builtin_amdgcn_global_load_lds(
        (const __attribute__((address_space(1))) unsigned int*)g,
        (__attribute__((address_space(3))) unsigned int*)(lds + seg * 512), 16,
        0, 0);
  }
}

#define GEMM_IDS                                       \
  int t = threadIdx.x, lane = t & 63, w = t >> 6;      \
  int ln = lane & 15, g = lane >> 4;                   \
  int wr = (w >> 1) << 6, wc = (w & 1) << 6;           \
  (void)wr; (void)wc;

#define MFMA_STEP(AS, BS)                                                      \
  {                                                                            \
    short8 af[4], bfr[4];                                                      \
    _Pragma("unroll") for (int mi = 0; mi < 4; ++mi) af[mi] =                  \
        lds_r8(AS, wr + mi * 16 + ln, g);                                      \
    _Pragma("unroll") for (int ni = 0; ni < 4; ++ni) bfr[ni] =                 \
        lds_r8(BS, wc + ni * 16 + ln, g);                                      \
    _Pragma("unroll") for (int mi = 0; mi < 4; ++mi)                           \
        _Pragma("unroll") for (int ni = 0; ni < 4; ++ni) acc[mi][ni] =         \
            __builtin_amdgcn_mfma_f32_16x16x32_bf16(af[mi], bfr[ni],           \
                                                    acc[mi][ni], 0, 0, 0);     \
  }

// -- prep: Ct_lh[l][h] = bf16(C[h][l]); Cb_hl[h][l] = bf16(C); s1 partials --
__global__ __launch_bounds__(256) void k_prep_c(const float* __restrict__ C,
                                                const float* __restrict__ w,
                                                short* __restrict__ Ct_lh,
                                                short* __restrict__ Cb_hl,
                                                float* __restrict__ s1p) {
  __shared__ float Ts[64][65];
  __shared__ float red[4][64];
  int b = blockIdx.z, h0 = blockIdx.y << 6, l0 = blockIdx.x << 6;
  int t = threadIdx.x;
  int hr = t >> 4, lc = (t & 15) << 2;
  const float* Cb = C + ((size_t)b * NH + h0) * NLC + l0;
#pragma unroll
  for (int i = 0; i < 4; ++i) {
    int h = hr + i * 16;
    float4 v = *(const float4*)&Cb[(size_t)h * NLC + lc];
    short4 cb;
    cb.x = bf16_of(v.x); cb.y = bf16_of(v.y);
    cb.z = bf16_of(v.z); cb.w = bf16_of(v.w);
    *(short4*)&Cb_hl[((size_t)b * NH + h0 + h) * NLC + l0 + lc] = cb;
    Ts[h][lc + 0] = v.x;
    Ts[h][lc + 1] = v.y;
    Ts[h][lc + 2] = v.z;
    Ts[h][lc + 3] = v.w;
  }
  __syncthreads();
  int lr = t >> 2, hc = (t & 3) << 4;
  short* dst = &Ct_lh[((size_t)b * NLC + l0 + lr) * NH + h0 + hc];
  short8 o0, o1;
#pragma unroll
  for (int j = 0; j < 8; ++j) o0[j] = bf16_of(Ts[hc + j][lr]);
#pragma unroll
  for (int j = 0; j < 8; ++j) o1[j] = bf16_of(Ts[hc + 8 + j][lr]);
  *(short8*)dst = o0;
  *(short8*)(dst + 8) = o1;
  // s1 partial: sum over this block's 64 h of C[h][l]*w1[h]
  int q = t >> 6, lq = t & 63;
  float a = 0.f;
#pragma unroll
  for (int j = 0; j < 16; ++j) a += Ts[(q << 4) + j][lq] * w[h0 + (q << 4) + j];
  red[q][lq] = a;
  __syncthreads();
  if (q == 0)
    s1p[((size_t)blockIdx.y * NB + b) * NLC + l0 + lq] =
        red[0][lq] + red[1][lq] + red[2][lq] + red[3][lq];
}

// ---- prep: Qtw3[m][h]=bf16(Q[h][m]*w3[h]); Qb_hm=bf16(Q); s2 partials;
// also folds the W_res f32->bf16 copy (512 elems per block). ----
__global__ __launch_bounds__(256) void k_prep_q(const float* __restrict__ Q,
                                                const float* __restrict__ w,
                                                const float* __restrict__ Wf,
                                                short* __restrict__ Qtw3,
                                                short* __restrict__ Qb_hm,
                                                short* __restrict__ Wb,
                                                float* __restrict__ s2p) {
  __shared__ float Ts[64][65];
  __shared__ float red[4][64];
  int b = blockIdx.z, h0 = blockIdx.y << 6, m0 = blockIdx.x << 6;
  int t = threadIdx.x;
  // W fold: linear block id in [0,512) covers 262144 elems, 2 per thread.
  {
    size_t wi =
        ((size_t)((blockIdx.z * 4 + blockIdx.y) * 4 + blockIdx.x) * 256 + t) *
        2;
    float2 wv = *(const float2*)&Wf[wi];
    short2 ws2;
    ws2.x = bf16_of(wv.x);
    ws2.y = bf16_of(wv.y);
    *(short2*)&Wb[wi] = ws2;
  }
  int hr = t >> 4, mc = (t & 15) << 2;
  const float* w3 = w + 2 * NH;
  const float* Qb = Q + ((size_t)b * NH + h0) * NLQ + m0;
#pragma unroll
  for (int i = 0; i < 4; ++i) {
    int h = hr + i * 16;
    float4 v = *(const float4*)&Qb[(size_t)h * NLQ + mc];
    short4 qb;
    qb.x = bf16_of(v.x); qb.y = bf16_of(v.y);
    qb.z = bf16_of(v.z); qb.w = bf16_of(v.w);
    *(short4*)&Qb_hm[((size_t)b * NH + h0 + h) * NLQ + m0 + mc] = qb;
    Ts[h][mc + 0] = v.x;
    Ts[h][mc + 1] = v.y;
    Ts[h][mc + 2] = v.z;
    Ts[h][mc + 3] = v.w;
  }
  __syncthreads();
  int mr = t >> 2, hc = (t & 3) << 4;
  short* dst = &Qtw3[((size_t)b * NLQ + m0 + mr) * NH + h0 + hc];
  short8 o0, o1;
#pragma unroll
  for (int j = 0; j < 8; ++j)
    o0[j] = bf16_of(Ts[hc + j][mr] * w3[h0 + hc + j]);
#pragma unroll
  for (int j = 0; j < 8; ++j)
    o1[j] = bf16_of(Ts[hc + 8 + j][mr] * w3[h0 + hc + 8 + j]);
  *(short8*)dst = o0;
  *(short8*)(dst + 8) = o1;
  // s2 partial over this block's 64 h, straight from the raw-Q LDS tile
  int q = t >> 6, mq = t & 63;
  const float* w2 = w + NH;
  float a = 0.f;
#pragma unroll
  for (int j = 0; j < 16; ++j)
    a += Ts[(q << 4) + j][mq] * w2[h0 + (q << 4) + j];
  red[q][mq] = a;
  __syncthreads();
  if (q == 0)
    s2p[((size_t)blockIdx.y * NB + b) * NLQ + m0 + mq] =
        red[0][mq] + red[1][mq] + red[2][mq] + red[3][mq];
}

// ------- S = Ct_lh @ Qtw3^T + s1 + s2  (M=l, N=m, K=h); 2-phase dbuf.
// Epilogue reduces s1p/s2p partials in-register and emits column-softmax
// partials straight from registers -> pmax/psum chunk = by.
__global__ __launch_bounds__(256) void k_sgemm(
    const short* __restrict__ Ct_lh, const short* __restrict__ Qtw3,
    const float* __restrict__ s1p, const float* __restrict__ s2p,
    const int* __restrict__ cmask, float* __restrict__ S,
    float* __restrict__ pmax, float* __restrict__ psum) {
  __shared__ short As[2][4096], Bs[2][4096];
  __shared__ float cmsh[128];
  __shared__ float sredm[4][4][16], sreds[4][4][16];
  XCD_SWZ(NLQ / 128, NLC / 128, NB, bx, by, bz)
  int b = bz, l0 = by << 7, m0 = bx << 7;
  GEMM_IDS
  const short* Ag = Ct_lh + ((size_t)b * NLC + l0) * NH;
  const short* Bg = Qtw3 + ((size_t)b * NLQ + m0) * NH;
  f32x4 acc[4][4] = {};
  stage_g(Ag, NH, As[0], t);
  stage_g(Bg, NH, Bs[0], t);
  __syncthreads();
  int cur = 0;
  for (int kn = 32; kn <= NH; kn += 32) {
    if (kn < NH) {
      stage_g(Ag + kn, NH, As[cur ^ 1], t);
      stage_g(Bg + kn, NH, Bs[cur ^ 1], t);
    }
    MFMA_STEP(As[cur], Bs[cur])
    __syncthreads();
    cur ^= 1;
  }
  // ---- epilogue: S write + column partials from registers ----
  if (t < 128) cmsh[t] = cmask[b * NLC + l0 + t] ? 0.f : NEGV;
  __syncthreads();
  const int N1 = NB * NLC, N2 = NB * NLQ;
  float s1r[16], ncr[16];
#pragma unroll
  for (int mi = 0; mi < 4; ++mi)
#pragma unroll
    for (int r = 0; r < 4; ++r) {
      int lloc = wr + mi * 16 + g * 4 + r;
      int gl = b * NLC + l0 + lloc;
      s1r[mi * 4 + r] =
          s1p[gl] + s1p[N1 + gl] + s1p[2 * N1 + gl] + s1p[3 * N1 + gl];
      ncr[mi * 4 + r] = cmsh[lloc];
    }
  float s2v[4], mxc[4], smc[4];
#pragma unroll
  for (int ni = 0; ni < 4; ++ni) {
    int gm = b * NLQ + m0 + wc + ni * 16 + ln;
    s2v[ni] = s2p[gm] + s2p[N2 + gm] + s2p[2 * N2 + gm] + s2p[3 * N2 + gm];
    mxc[ni] = -INFINITY;
    smc[ni] = 0.f;
  }
#pragma unroll
  for (int ni = 0; ni < 4; ++ni)
#pragma unroll
    for (int mi = 0; mi < 4; ++mi)
#pragma unroll
      for (int r = 0; r < 4; ++r)
        mxc[ni] = fmaxf(mxc[ni],
                        acc[mi][ni][r] + s1r[mi * 4 + r] + s2v[ni] +
                            ncr[mi * 4 + r]);
#pragma unroll
  for (int ni = 0; ni < 4; ++ni) {
    int m = m0 + wc + ni * 16 + ln;
#pragma unroll
    for (int mi = 0; mi < 4; ++mi)
#pragma unroll
      for (int r = 0; r < 4; ++r) {
        int l = l0 + wr + mi * 16 + g * 4 + r;
        float sv = acc[mi][ni][r] + s1r[mi * 4 + r] + s2v[ni];
        S[((size_t)b * NLC + l) * NLQ + m] = sv;
        smc[ni] += expf(sv + ncr[mi * 4 + r] - mxc[ni]);
      }
  }
  // butterfly across the 4 lane-groups (same ln, different g)
#pragma unroll
  for (int off = 16; off <= 32; off <<= 1)
#pragma unroll
    for (int ni = 0; ni < 4; ++ni) {
      float m2 = __shfl_xor(mxc[ni], off);
      float s2x = __shfl_xor(smc[ni], off);
      float nm = fmaxf(mxc[ni], m2);
      smc[ni] = smc[ni] * expf(mxc[ni] - nm) + s2x * expf(m2 - nm);
      mxc[ni] = nm;
    }
  if (lane < 16) {
#pragma unroll
    for (int ni = 0; ni < 4; ++ni) {
      sredm[w][ni][lane] = mxc[ni];
      sreds[w][ni][lane] = smc[ni];
    }
  }
  __syncthreads();
  if (t < 128) {
    int wcsel = t >> 6, nii = (t >> 4) & 3, lnn = t & 15;
    float mA = sredm[wcsel][nii][lnn], sA = sreds[wcsel][nii][lnn];
    float mB = sredm[wcsel + 2][nii][lnn], sB = sreds[wcsel + 2][nii][lnn];
    float nm = fmaxf(mA, mB);
    float sm = sA * expf(mA - nm) + sB * expf(mB - nm);
    int m = m0 + (wcsel << 6) + nii * 16 + lnn;
    size_t base = ((size_t)b * NLQ + m) * TCH + by;
    pmax[base] = nm;
    psum[base] = sm;
  }
}

// ---- row+col softmax, IN PLACE, with colfin FOLDED (cmax/cinv from pmax/
// psum partials, reduced once per block into LDS). Block = 16 rows.
__global__ __launch_bounds__(256) void k_rowsoft(float* __restrict__ S,
                                                 const int* __restrict__ qmask,
                                                 const int* __restrict__ cmask,
                                                 const float* __restrict__ pmax,
                                                 const float* __restrict__ psum) {
  __shared__ float cmsh[256], cish[256];
  int t = threadIdx.x, wave = t >> 6, lane = t & 63;
  int base = blockIdx.x << 4;  // first row (16 rows/block, never straddles b)
  int b = base >> 10;
  {  // folded colfin: thread t reduces column m=t of batch b
    const float* pm = pmax + ((size_t)(b << 8) + t) * TCH;
    const float* ps = psum + ((size_t)(b << 8) + t) * TCH;
    float mx = pm[0], sm = ps[0];
#pragma unroll
    for (int c = 1; c < TCH; ++c) {
      float m2 = pm[c], s2 = ps[c];
      float nm = fmaxf(mx, m2);
      sm = sm * expf(mx - nm) + s2 * expf(m2 - nm);
      mx = nm;
    }
    cmsh[t] = mx;
    cish[t] = 1.0f / sm;
  }
  __syncthreads();
  int m4 = lane << 2;
  const int* qm = qmask + b * NLQ;
  int4 q = *(const int4*)&qm[m4];
  float nq0 = q.x ? 0.f : NEGV, nq1 = q.y ? 0.f : NEGV;
  float nq2 = q.z ? 0.f : NEGV, nq3 = q.w ? 0.f : NEGV;
  float4 cm4 = *(const float4*)&cmsh[m4];
  float4 ci4 = *(const float4*)&cish[m4];
#pragma unroll
  for (int i = 0; i < 4; ++i) {
    int idx = base + wave * 4 + i;
    float* row = S + (size_t)idx * NLQ;
    float4 v = *(const float4*)&row[m4];
    float x0 = v.x + nq0, x1 = v.y + nq1, x2 = v.z + nq2, x3 = v.w + nq3;
    float mx = fmaxf(fmaxf(x0, x1), fmaxf(x2, x3));
#pragma unroll
    for (int off = 32; off > 0; off >>= 1) mx = fmaxf(mx, __shfl_xor(mx, off));
    float p0 = expf(x0 - mx), p1 = expf(x1 - mx);
    float p2 = expf(x2 - mx), p3 = expf(x3 - mx);
    float sm = p0 + p1 + p2 + p3;
#pragma unroll
    for (int off = 32; off > 0; off >>= 1) sm += __shfl_xor(sm, off);
    float iv = 1.0f / sm;
    short4 o;
    o.x = bf16_of(p0 * iv);
    o.y = bf16_of(p1 * iv);
    o.z = bf16_of(p2 * iv);
    o.w = bf16_of(p3 * iv);
    float cmf = (float)cmask[idx];
    short4 oc;
    oc.x = bf16_of(expf(v.x - cm4.x) * ci4.x * cmf);
    oc.y = bf16_of(expf(v.y - cm4.y) * ci4.y * cmf);
    oc.z = bf16_of(expf(v.z - cm4.z) * ci4.z * cmf);
    oc.w = bf16_of(expf(v.w - cm4.w) * ci4.w * cmf);
    *(short4*)((short*)row + m4) = o;
    *(short4*)((short*)row + 256 + m4) = oc;
  }
}

// ------ Tpb[ks][b][h][m] = sum_{l in chunk ks} C[h][l] * P_col[l][m] ------
// split-K partials (bf16); M=h, N=m, K=l chunk of 256.
// A: bf16 Cb_hl via stage_g (DMA). B: bf16 P_col transposed scatter.
__global__ __launch_bounds__(256) void k_tgemm(const short* __restrict__ Cb_hl,
                                               const short* __restrict__ PcolS,
                                               short* __restrict__ Tpb) {
  __shared__ short As[4096], Bs[4096];
  XCD_SWZ(4, KSPLIT, NB, bx, by, bz)
  int b = bz;
  int ks = by;
  int h0 = (bx & 1) << 7;
  int m0 = (bx >> 1) << 7;
  GEMM_IDS
  const short* Ag = Cb_hl + ((size_t)b * NH + h0) * NLC;
  const short* Pb = PcolS + (size_t)b * NLC * 512 + 256 + m0;
  f32x4 acc[4][4] = {};
  int kbeg = ks * (NLC / KSPLIT), kend = kbeg + NLC / KSPLIT;
  int lloc = t >> 3, g2 = lloc >> 3, kin = lloc & 7;
  int mbase = (t & 7) << 4;
  for (int k0 = kbeg; k0 < kend; k0 += 32) {
    __syncthreads();
    stage_g(Ag + k0, NLC, As, t);
    {  // B: bf16 P_col passthrough, transposed into swizzled LDS
      const short* srow = Pb + (size_t)(k0 + lloc) * 512;
      short8 x0 = *(const short8*)&srow[mbase];
      short8 x1 = *(const short8*)&srow[mbase + 8];
#pragma unroll
      for (int j = 0; j < 8; ++j) {
        int R = mbase + j;
        int byteoff =
            (R << 6) + (((g2 ^ ((R >> 1) & 3)) & 3) << 4) + (kin << 1);
        *(short*)((char*)Bs + byteoff) = x0[j];
      }
#pragma unroll
      for (int j = 0; j < 8; ++j) {
        int R = mbase + 8 + j;
        int byteoff =
            (R << 6) + (((g2 ^ ((R >> 1) & 3)) & 3) << 4) + (kin << 1);
        *(short*)((char*)Bs + byteoff) = x1[j];
      }
    }
    __syncthreads();
    MFMA_STEP(As, Bs)
  }
  short* dst = Tpb + ((size_t)ks * NB + b) * NH * NLQ;
#pragma unroll
  for (int mi = 0; mi < 4; ++mi)
#pragma unroll
    for (int ni = 0; ni < 4; ++ni)
#pragma unroll
      for (int r = 0; r < 4; ++r) {
        int h = h0 + wr + mi * 16 + g * 4 + r;
        int m = m0 + wc + ni * 16 + ln;
        dst[(size_t)h * NLQ + m] = bf16_of(acc[mi][ni][r]);
      }
}

// reduce KSPLIT bf16 partials -> bf16 Tt[b][h][m], 8 elems/thread
__global__ __launch_bounds__(256) void k_tfin(const short* __restrict__ Tpb,
                                              short* __restrict__ Tt) {
  size_t i = ((size_t)blockIdx.x * 256 + threadIdx.x) * 8;
  const size_t stride = (size_t)NB * NH * NLQ;
  short8 x0 = *(const short8*)&Tpb[i];
  short8 x1 = *(const short8*)&Tpb[i + stride];
  short8 x2 = *(const short8*)&Tpb[i + 2 * stride];
  short8 x3 = *(const short8*)&Tpb[i + 3 * stride];
  short8 o;
#pragma unroll
  for (int j = 0; j < 8; ++j)
    o[j] = bf16_of(f_of(x0[j]) + f_of(x1[j]) + f_of(x2[j]) + f_of(x3[j]));
  *(short8*)&Tt[i] = o;
}

// ---- [A | Ct*Bv][l][h] = f(sum_m P_row[l][m] * X[h][m]); 2-phase dbuf.
// nb<2 epilogue ALSO writes CtA_lh = Ct*A so k_out stages it via pure DMA.
__global__ __launch_bounds__(256) void k_abgemm(
    const short* __restrict__ Prow, const short* __restrict__ Qb_hm,
    const short* __restrict__ Tt, const short* __restrict__ Ct_lh,
    short* __restrict__ A_lh, short* __restrict__ CtA_lh,
    short* __restrict__ CtBv_lh) {
  __shared__ short As[2][4096], Bs[2][4096];
  XCD_SWZ(4, NLC / 128, NB, bx, by, bz)
  int b = bz, l0 = by << 7, nb = bx;
  GEMM_IDS
  const short* Ag = Prow + ((size_t)b * NLC + l0) * 512;
  const short* Bbase = (nb < 2)
                           ? Qb_hm + ((size_t)b * NH + nb * 128) * NLQ
                           : Tt + ((size_t)b * NH + (nb - 2) * 128) * NLQ;
  f32x4 acc[4][4] = {};
  stage_g(Ag, 512, As[0], t);
  stage_g(Bbase, NLQ, Bs[0], t);
  __syncthreads();
  int cur = 0;
  for (int kn = 32; kn <= NLQ; kn += 32) {
    if (kn < NLQ) {
      stage_g(Ag + kn, 512, As[cur ^ 1], t);
      stage_g(Bbase + kn, NLQ, Bs[cur ^ 1], t);
    }
    MFMA_STEP(As[cur], Bs[cur])
    __syncthreads();
    cur ^= 1;
  }
  int hbase = (nb & 1) << 7;
  if (nb < 2) {
#pragma unroll
    for (int mi = 0; mi < 4; ++mi)
#pragma unroll
      for (int ni = 0; ni < 4; ++ni)
#pragma unroll
        for (int r = 0; r < 4; ++r) {
          int l = l0 + wr + mi * 16 + g * 4 + r;
          int h = hbase + wc + ni * 16 + ln;
          size_t off = ((size_t)b * NLC + l) * NH + h;
          float a = acc[mi][ni][r];
          A_lh[off] = bf16_of(a);
          CtA_lh[off] = bf16_of(f_of(Ct_lh[off]) * a);
        }
  } else {
#pragma unroll
    for (int mi = 0; mi < 4; ++mi)
#pragma unroll
      for (int ni = 0; ni < 4; ++ni)
#pragma unroll
        for (int r = 0; r < 4; ++r) {
          int l = l0 + wr + mi * 16 + g * 4 + r;
          int h = hbase + wc + ni * 16 + ln;
          size_t off = ((size_t)b * NLC + l) * NH + h;
          CtBv_lh[off] = bf16_of(f_of(Ct_lh[off]) * acc[mi][ni][r]);
        }
  }
}

// -------- out[h][l] = relu(b + sum_f W[h][f]*cat[l][f]); 2-phase dbuf --------
// cat regions along f: [Ct | A | Ct*A | Ct*Bv] -- ALL pure stage_g DMA.
__global__ __launch_bounds__(256) void k_out(
    const short* __restrict__ Wb, const short* __restrict__ Ct_lh,
    const short* __restrict__ A_lh, const short* __restrict__ CtA_lh,
    const short* __restrict__ CtBv_lh, const float* __restrict__ br,
    float* __restrict__ out) {
  __shared__ short As[2][4096], Bs[2][4096];
  XCD_SWZ(NLC / 128, NH / 128, NB, bx, by, bz)
  int b = bz, h0 = by << 7, l0 = bx << 7;
  GEMM_IDS
  const short* Wg = Wb + (size_t)h0 * (4 * NH);
  size_t boff = ((size_t)b * NLC + l0) * NH;
  f32x4 acc[4][4] = {};
  stage_g(Wg, 4 * NH, As[0], t);
  stage_g(Ct_lh + boff, NH, Bs[0], t);  // tile 0 is region 0 (Ct)
  __syncthreads();
  int cur = 0;
  for (int kn = 32; kn <= 4 * NH; kn += 32) {
    bool has = kn < 4 * NH;
    if (has) {
      stage_g(Wg + kn, 4 * NH, As[cur ^ 1], t);
      int regn = kn >> 8, kon = kn & 255;
      const short* base = (regn == 0) ? Ct_lh
                          : (regn == 1) ? A_lh
                          : (regn == 2) ? CtA_lh : CtBv_lh;
      stage_g(base + boff + kon, NH, Bs[cur ^ 1], t);
    }
    MFMA_STEP(As[cur], Bs[cur])
    __syncthreads();
    cur ^= 1;
  }
#pragma unroll
  for (int mi = 0; mi < 4; ++mi)
#pragma unroll
    for (int ni = 0; ni < 4; ++ni) {
      int h = h0 + wr + mi * 16 + g * 4;
      int l = l0 + wc + ni * 16 + ln;
#pragma unroll
      for (int r = 0; r < 4; ++r) {
        float bias = br[h + r];
        out[((size_t)b * NH + h + r) * NLC + l] =
            fmaxf(acc[mi][ni][r] + bias, 0.f);
      }
    }
}

extern "C" void kernel_launch(void* const* d_in, const int* in_sizes, int n_in,
                              void* d_out, int out_size, void* d_ws,
                              size_t ws_size, hipStream_t stream) {
  (void)in_sizes;
  (void)n_in;
  (void)out_size;
  (void)ws_size;
  const float* C = (const float*)d_in[0];
  const float* Q = (const float*)d_in[1];
  const int* cmask = (const int*)d_in[2];
  const int* qmask = (const int*)d_in[3];
  const float* w = (const float*)d_in[4];
  const float* W = (const float*)d_in[5];
  const float* br = (const float*)d_in[6];
  float* out = (float*)d_out;

  char* p = (char*)d_ws;
  float* S = (float*)p;       p += (size_t)NB * NLC * NLQ * 4;   // 33.6 MB
  short* Ct_lh = (short*)p;   p += (size_t)NB * NLC * NH * 2;    // 16.8 MB
  short* A_lh = (short*)p;    p += (size_t)NB * NLC * NH * 2;    // 16.8 MB
  short* CtBv_lh = (short*)p; p += (size_t)NB * NLC * NH * 2;    // 16.8 MB
  short* CtA_lh = (short*)p;  p += (size_t)NB * NLC * NH * 2;    // 16.8 MB
  short* Cb_hl = (short*)p;   p += (size_t)NB * NH * NLC * 2;    // 16.8 MB
  short* Tt = (short*)p;      p += (size_t)NB * NH * NLQ * 2;    // 4.2 MB
  short* Qtw3 = (short*)p;    p += (size_t)NB * NLQ * NH * 2;    // 4.2 MB
  short* Qb_hm = (short*)p;   p += (size_t)NB * NH * NLQ * 2;    // 4.2 MB
  short* Wb = (short*)p;      p += (size_t)NH * 4 * NH * 2;      // 0.5 MB
  float* pmax = (float*)p;    p += (size_t)NB * NLQ * TCH * 4;
  float* psum = (float*)p;    p += (size_t)NB * NLQ * TCH * 4;
  float* s1p = (float*)p;     p += (size_t)4 * NB * NLC * 4;     // 0.5 MB
  float* s2p = (float*)p;     p += (size_t)4 * NB * NLQ * 4;     // 0.13 MB
  // tgemm split-K bf16 partials: reuse A_lh (16.8 MB, dead until abgemm).
  short* Tpb = A_lh;
  // in-place softmax: bf16 P_row at bytes 0..511, P_col at 512..1023 of each
  // 1KB S row (row stride 512 shorts).
  short* Prow = (short*)S;

  k_prep_c<<<dim3(NLC / 64, NH / 64, NB), dim3(256), 0, stream>>>(C, w, Ct_lh,
                                                                  Cb_hl, s1p);
  k_prep_q<<<dim3(NLQ / 64, NH / 64, NB), dim3(256), 0, stream>>>(
      Q, w, W, Qtw3, Qb_hm, Wb, s2p);
  k_sgemm<<<dim3(NLQ / 128, NLC / 128, NB), dim3(256), 0, stream>>>(
      Ct_lh, Qtw3, s1p, s2p, cmask, S, pmax, psum);
  k_rowsoft<<<dim3(NB * NLC / 16), dim3(256), 0, stream>>>(S, qmask, cmask,
                                                           pmax, psum);
  k_tgemm<<<dim3(4, KSPLIT, NB), dim3(256), 0, stream>>>(Cb_hl, Prow, Tpb);
  k_tfin<<<dim3(NB * NH * NLQ / 2048), dim3(256), 0, stream>>>(Tpb, Tt);
  k_abgemm<<<dim3(4, NLC / 128, NB), dim3(256), 0, stream>>>(
      Prow, Qb_hm, Tt, Ct_lh, A_lh, CtA_lh, CtBv_lh);
  k_out<<<dim3(NLC / 128, NH / 128, NB), dim3(256), 0, stream>>>(
      Wb, Ct_lh, A_lh, CtA_lh, CtBv_lh, br, out);
}

// Round 16
// 132.741 us; speedup vs baseline: 1.0370x; 1.0146x over previous
//
#include <hip/hip_runtime.h>
#include <math.h>

#define NB 32
#define NH 256
#define NLC 1024
#define NLQ 256
#define NEGV (-1e30f)
#define TCH 8      // column-stats l-chunks (each 128 rows, = sgemm l-tile)
#define KSPLIT 4   // tgemm split-K factor

typedef short short8 __attribute__((ext_vector_type(8)));
typedef float f32x4 __attribute__((ext_vector_type(4)));

__device__ inline short bf16_of(float f) {
  union { float f; unsigned u; } v;
  v.f = f;
  unsigned r = (v.u + 0x7fffu + ((v.u >> 16) & 1u)) >> 16;
  return (short)r;
}
__device__ inline float f_of(short s) {
  union { unsigned u; float f; } v;
  v.u = ((unsigned)(unsigned short)s) << 16;
  return v.f;
}
__device__ inline short8 cvt8(float4 a, float4 b) {
  short8 o;
  o[0] = bf16_of(a.x); o[1] = bf16_of(a.y); o[2] = bf16_of(a.z); o[3] = bf16_of(a.w);
  o[4] = bf16_of(b.x); o[5] = bf16_of(b.y); o[6] = bf16_of(b.z); o[7] = bf16_of(b.w);
  return o;
}

// XCD-aware bijective block swizzle (T1): consecutive logical tiles land on
// the same XCD's L2 so operand-sharing neighbor blocks hit instead of miss.
// Requires nwg % 8 == 0 (all our GEMM grids are).
#define XCD_SWZ(GX, GY, GZ, bx, by, bz)                                 \
  int bx, by, bz;                                                       \
  {                                                                     \
    int _lin = blockIdx.x + (GX) * (blockIdx.y + (GY) * blockIdx.z);    \
    const int _nwg = (GX) * (GY) * (GZ);                                \
    _lin = (_lin & 7) * (_nwg >> 3) + (_lin >> 3);                      \
    bx = _lin % (GX);                                                   \
    by = (_lin / (GX)) % (GY);                                          \
    bz = _lin / ((GX) * (GY));                                          \
  }

// ---- swizzled 128x32 bf16 LDS tile helpers (row = 64B, slot ^= (row>>1)&3) ----
__device__ inline void lds_w8(short* lds, int r, int c, short8 v) {
  int byteoff = (r << 6) + (((c ^ ((r >> 1) & 3)) & 3) << 4);
  *(short8*)((char*)lds + byteoff) = v;
}
__device__ inline short8 lds_r8(const short* lds, int R, int g) {
  int byteoff = (R << 6) + (((g ^ ((R >> 1) & 3)) & 3) << 4);
  return *(const short8*)((const char*)lds + byteoff);
}
// global_load_lds staging of a 128x32 bf16 tile from K-minor src (ld elements).
// Source group pre-permuted per-lane so linear LDS bytes match swizzled reads.
__device__ inline void stage_g(const short* src, int ld, short* lds, int t) {
  int L = t & 63, w = t >> 6;
  int cp = (L & 3) ^ ((L >> 3) & 3);
#pragma unroll
  for (int i = 0; i < 2; ++i) {
    int seg = w + i * 4;
    const short* g = src + (size_t)(seg * 16 + (L >> 2)) * ld + cp * 8;
    __builtin_amdgcn_global_load_lds(
        (const __attribute__((address_space(1))) unsigned int*)g,
        (__attribute__((address_space(3))) unsigned int*)(lds + seg * 512), 16,
        0, 0);
  }
}

#define GEMM_IDS                                       \
  int t = threadIdx.x, lane = t & 63, w = t >> 6;      \
  int ln = lane & 15, g = lane >> 4;                   \
  int wr = (w >> 1) << 6, wc = (w & 1) << 6;           \
  (void)wr; (void)wc;

#define MFMA_STEP(AS, BS)                                                      \
  {                                                                            \
    short8 af[4], bfr[4];                                                      \
    _Pragma("unroll") for (int mi = 0; mi < 4; ++mi) af[mi] =                  \
        lds_r8(AS, wr + mi * 16 + ln, g);                                      \
    _Pragma("unroll") for (int ni = 0; ni < 4; ++ni) bfr[ni] =                 \
        lds_r8(BS, wc + ni * 16 + ln, g);                                      \
    _Pragma("unroll") for (int mi = 0; mi < 4; ++mi)                           \
        _Pragma("unroll") for (int ni = 0; ni < 4; ++ni) acc[mi][ni] =         \
            __builtin_amdgcn_mfma_f32_16x16x32_bf16(af[mi], bfr[ni],           \
                                                    acc[mi][ni], 0, 0, 0);     \
  }

// -- merged prep: blocks [0,2048) do C-side, [2048,2560) do Q-side + W fold.
// C-side: Ct_lh[l][h]=bf16(C[h][l]); Cb_hl[h][l]=bf16(C); s1 partials.
// Q-side: Qtw3[m][h]=bf16(Q[h][m]*w3[h]); Qb_hm=bf16(Q); s2 partials; Wb.
__global__ __launch_bounds__(256) void k_prep(
    const float* __restrict__ C, const float* __restrict__ Q,
    const float* __restrict__ w, const float* __restrict__ Wf,
    short* __restrict__ Ct_lh, short* __restrict__ Cb_hl,
    short* __restrict__ Qtw3, short* __restrict__ Qb_hm,
    short* __restrict__ Wb, float* __restrict__ s1p,
    float* __restrict__ s2p) {
  __shared__ float Ts[64][65];
  __shared__ float red[4][64];
  int bid = blockIdx.x;
  int t = threadIdx.x;
  if (bid < 2048) {
    // ---- C side: l-blk = bid&15, h-blk = (bid>>4)&3, b = bid>>6 ----
    int b = bid >> 6, hb = (bid >> 4) & 3, lb = bid & 15;
    int h0 = hb << 6, l0 = lb << 6;
    int hr = t >> 4, lc = (t & 15) << 2;
    const float* Cb = C + ((size_t)b * NH + h0) * NLC + l0;
#pragma unroll
    for (int i = 0; i < 4; ++i) {
      int h = hr + i * 16;
      float4 v = *(const float4*)&Cb[(size_t)h * NLC + lc];
      short4 cb;
      cb.x = bf16_of(v.x); cb.y = bf16_of(v.y);
      cb.z = bf16_of(v.z); cb.w = bf16_of(v.w);
      *(short4*)&Cb_hl[((size_t)b * NH + h0 + h) * NLC + l0 + lc] = cb;
      Ts[h][lc + 0] = v.x;
      Ts[h][lc + 1] = v.y;
      Ts[h][lc + 2] = v.z;
      Ts[h][lc + 3] = v.w;
    }
    __syncthreads();
    int lr = t >> 2, hc = (t & 3) << 4;
    short* dst = &Ct_lh[((size_t)b * NLC + l0 + lr) * NH + h0 + hc];
    short8 o0, o1;
#pragma unroll
    for (int j = 0; j < 8; ++j) o0[j] = bf16_of(Ts[hc + j][lr]);
#pragma unroll
    for (int j = 0; j < 8; ++j) o1[j] = bf16_of(Ts[hc + 8 + j][lr]);
    *(short8*)dst = o0;
    *(short8*)(dst + 8) = o1;
    // s1 partial: sum over this block's 64 h of C[h][l]*w1[h]
    int q = t >> 6, lq = t & 63;
    float a = 0.f;
#pragma unroll
    for (int j = 0; j < 16; ++j)
      a += Ts[(q << 4) + j][lq] * w[h0 + (q << 4) + j];
    red[q][lq] = a;
    __syncthreads();
    if (q == 0)
      s1p[((size_t)hb * NB + b) * NLC + l0 + lq] =
          red[0][lq] + red[1][lq] + red[2][lq] + red[3][lq];
  } else {
    // ---- Q side: qid in [0,512): m-blk = qid&3, h-blk = (qid>>2)&3,
    // b = qid>>4 ----
    int qid = bid - 2048;
    int b = qid >> 4, hb = (qid >> 2) & 3, mb = qid & 3;
    int h0 = hb << 6, m0 = mb << 6;
    {  // W fold: 512 blocks cover 262144 elems, 2 per thread.
      size_t wi = ((size_t)qid * 256 + t) * 2;
      float2 wv = *(const float2*)&Wf[wi];
      short2 ws2;
      ws2.x = bf16_of(wv.x);
      ws2.y = bf16_of(wv.y);
      *(short2*)&Wb[wi] = ws2;
    }
    int hr = t >> 4, mc = (t & 15) << 2;
    const float* w3 = w + 2 * NH;
    const float* Qb = Q + ((size_t)b * NH + h0) * NLQ + m0;
#pragma unroll
    for (int i = 0; i < 4; ++i) {
      int h = hr + i * 16;
      float4 v = *(const float4*)&Qb[(size_t)h * NLQ + mc];
      short4 qb;
      qb.x = bf16_of(v.x); qb.y = bf16_of(v.y);
      qb.z = bf16_of(v.z); qb.w = bf16_of(v.w);
      *(short4*)&Qb_hm[((size_t)b * NH + h0 + h) * NLQ + m0 + mc] = qb;
      Ts[h][mc + 0] = v.x;
      Ts[h][mc + 1] = v.y;
      Ts[h][mc + 2] = v.z;
      Ts[h][mc + 3] = v.w;
    }
    __syncthreads();
    int mr = t >> 2, hc = (t & 3) << 4;
    short* dst = &Qtw3[((size_t)b * NLQ + m0 + mr) * NH + h0 + hc];
    short8 o0, o1;
#pragma unroll
    for (int j = 0; j < 8; ++j)
      o0[j] = bf16_of(Ts[hc + j][mr] * w3[h0 + hc + j]);
#pragma unroll
    for (int j = 0; j < 8; ++j)
      o1[j] = bf16_of(Ts[hc + 8 + j][mr] * w3[h0 + hc + 8 + j]);
    *(short8*)dst = o0;
    *(short8*)(dst + 8) = o1;
    // s2 partial over this block's 64 h, straight from the raw-Q LDS tile
    int q = t >> 6, mq = t & 63;
    const float* w2 = w + NH;
    float a = 0.f;
#pragma unroll
    for (int j = 0; j < 16; ++j)
      a += Ts[(q << 4) + j][mq] * w2[h0 + (q << 4) + j];
    red[q][mq] = a;
    __syncthreads();
    if (q == 0)
      s2p[((size_t)hb * NB + b) * NLQ + m0 + mq] =
          red[0][mq] + red[1][mq] + red[2][mq] + red[3][mq];
  }
}

// ------- S = Ct_lh @ Qtw3^T + s1 + s2  (M=l, N=m, K=h); 2-phase dbuf.
// Epilogue reduces s1p/s2p partials in-register and emits column-softmax
// partials straight from registers -> pmax/psum chunk = by.
__global__ __launch_bounds__(256) void k_sgemm(
    const short* __restrict__ Ct_lh, const short* __restrict__ Qtw3,
    const float* __restrict__ s1p, const float* __restrict__ s2p,
    const int* __restrict__ cmask, float* __restrict__ S,
    float* __restrict__ pmax, float* __restrict__ psum) {
  __shared__ short As[2][4096], Bs[2][4096];
  __shared__ float cmsh[128];
  __shared__ float sredm[4][4][16], sreds[4][4][16];
  XCD_SWZ(NLQ / 128, NLC / 128, NB, bx, by, bz)
  int b = bz, l0 = by << 7, m0 = bx << 7;
  GEMM_IDS
  const short* Ag = Ct_lh + ((size_t)b * NLC + l0) * NH;
  const short* Bg = Qtw3 + ((size_t)b * NLQ + m0) * NH;
  f32x4 acc[4][4] = {};
  stage_g(Ag, NH, As[0], t);
  stage_g(Bg, NH, Bs[0], t);
  __syncthreads();
  int cur = 0;
  for (int kn = 32; kn <= NH; kn += 32) {
    if (kn < NH) {
      stage_g(Ag + kn, NH, As[cur ^ 1], t);
      stage_g(Bg + kn, NH, Bs[cur ^ 1], t);
    }
    MFMA_STEP(As[cur], Bs[cur])
    __syncthreads();
    cur ^= 1;
  }
  // ---- epilogue: S write + column partials from registers ----
  if (t < 128) cmsh[t] = cmask[b * NLC + l0 + t] ? 0.f : NEGV;
  __syncthreads();
  const int N1 = NB * NLC, N2 = NB * NLQ;
  float s1r[16], ncr[16];
#pragma unroll
  for (int mi = 0; mi < 4; ++mi)
#pragma unroll
    for (int r = 0; r < 4; ++r) {
      int lloc = wr + mi * 16 + g * 4 + r;
      int gl = b * NLC + l0 + lloc;
      s1r[mi * 4 + r] =
          s1p[gl] + s1p[N1 + gl] + s1p[2 * N1 + gl] + s1p[3 * N1 + gl];
      ncr[mi * 4 + r] = cmsh[lloc];
    }
  float s2v[4], mxc[4], smc[4];
#pragma unroll
  for (int ni = 0; ni < 4; ++ni) {
    int gm = b * NLQ + m0 + wc + ni * 16 + ln;
    s2v[ni] = s2p[gm] + s2p[N2 + gm] + s2p[2 * N2 + gm] + s2p[3 * N2 + gm];
    mxc[ni] = -INFINITY;
    smc[ni] = 0.f;
  }
#pragma unroll
  for (int ni = 0; ni < 4; ++ni)
#pragma unroll
    for (int mi = 0; mi < 4; ++mi)
#pragma unroll
      for (int r = 0; r < 4; ++r)
        mxc[ni] = fmaxf(mxc[ni],
                        acc[mi][ni][r] + s1r[mi * 4 + r] + s2v[ni] +
                            ncr[mi * 4 + r]);
#pragma unroll
  for (int ni = 0; ni < 4; ++ni) {
    int m = m0 + wc + ni * 16 + ln;
#pragma unroll
    for (int mi = 0; mi < 4; ++mi)
#pragma unroll
      for (int r = 0; r < 4; ++r) {
        int l = l0 + wr + mi * 16 + g * 4 + r;
        float sv = acc[mi][ni][r] + s1r[mi * 4 + r] + s2v[ni];
        S[((size_t)b * NLC + l) * NLQ + m] = sv;
        smc[ni] += expf(sv + ncr[mi * 4 + r] - mxc[ni]);
      }
  }
  // butterfly across the 4 lane-groups (same ln, different g)
#pragma unroll
  for (int off = 16; off <= 32; off <<= 1)
#pragma unroll
    for (int ni = 0; ni < 4; ++ni) {
      float m2 = __shfl_xor(mxc[ni], off);
      float s2x = __shfl_xor(smc[ni], off);
      float nm = fmaxf(mxc[ni], m2);
      smc[ni] = smc[ni] * expf(mxc[ni] - nm) + s2x * expf(m2 - nm);
      mxc[ni] = nm;
    }
  if (lane < 16) {
#pragma unroll
    for (int ni = 0; ni < 4; ++ni) {
      sredm[w][ni][lane] = mxc[ni];
      sreds[w][ni][lane] = smc[ni];
    }
  }
  __syncthreads();
  if (t < 128) {
    int wcsel = t >> 6, nii = (t >> 4) & 3, lnn = t & 15;
    float mA = sredm[wcsel][nii][lnn], sA = sreds[wcsel][nii][lnn];
    float mB = sredm[wcsel + 2][nii][lnn], sB = sreds[wcsel + 2][nii][lnn];
    float nm = fmaxf(mA, mB);
    float sm = sA * expf(mA - nm) + sB * expf(mB - nm);
    int m = m0 + (wcsel << 6) + nii * 16 + lnn;
    size_t base = ((size_t)b * NLQ + m) * TCH + by;
    pmax[base] = nm;
    psum[base] = sm;
  }
}

// ---- row+col softmax, IN PLACE, with colfin FOLDED (cmax/cinv from pmax/
// psum partials, reduced once per block into LDS). Block = 16 rows.
__global__ __launch_bounds__(256) void k_rowsoft(float* __restrict__ S,
                                                 const int* __restrict__ qmask,
                                                 const int* __restrict__ cmask,
                                                 const float* __restrict__ pmax,
                                                 const float* __restrict__ psum) {
  __shared__ float cmsh[256], cish[256];
  int t = threadIdx.x, wave = t >> 6, lane = t & 63;
  int base = blockIdx.x << 4;  // first row (16 rows/block, never straddles b)
  int b = base >> 10;
  {  // folded colfin: thread t reduces column m=t of batch b
    const float* pm = pmax + ((size_t)(b << 8) + t) * TCH;
    const float* ps = psum + ((size_t)(b << 8) + t) * TCH;
    float mx = pm[0], sm = ps[0];
#pragma unroll
    for (int c = 1; c < TCH; ++c) {
      float m2 = pm[c], s2 = ps[c];
      float nm = fmaxf(mx, m2);
      sm = sm * expf(mx - nm) + s2 * expf(m2 - nm);
      mx = nm;
    }
    cmsh[t] = mx;
    cish[t] = 1.0f / sm;
  }
  __syncthreads();
  int m4 = lane << 2;
  const int* qm = qmask + b * NLQ;
  int4 q = *(const int4*)&qm[m4];
  float nq0 = q.x ? 0.f : NEGV, nq1 = q.y ? 0.f : NEGV;
  float nq2 = q.z ? 0.f : NEGV, nq3 = q.w ? 0.f : NEGV;
  float4 cm4 = *(const float4*)&cmsh[m4];
  float4 ci4 = *(const float4*)&cish[m4];
#pragma unroll
  for (int i = 0; i < 4; ++i) {
    int idx = base + wave * 4 + i;
    float* row = S + (size_t)idx * NLQ;
    float4 v = *(const float4*)&row[m4];
    float x0 = v.x + nq0, x1 = v.y + nq1, x2 = v.z + nq2, x3 = v.w + nq3;
    float mx = fmaxf(fmaxf(x0, x1), fmaxf(x2, x3));
#pragma unroll
    for (int off = 32; off > 0; off >>= 1) mx = fmaxf(mx, __shfl_xor(mx, off));
    float p0 = expf(x0 - mx), p1 = expf(x1 - mx);
    float p2 = expf(x2 - mx), p3 = expf(x3 - mx);
    float sm = p0 + p1 + p2 + p3;
#pragma unroll
    for (int off = 32; off > 0; off >>= 1) sm += __shfl_xor(sm, off);
    float iv = 1.0f / sm;
    short4 o;
    o.x = bf16_of(p0 * iv);
    o.y = bf16_of(p1 * iv);
    o.z = bf16_of(p2 * iv);
    o.w = bf16_of(p3 * iv);
    float cmf = (float)cmask[idx];
    short4 oc;
    oc.x = bf16_of(expf(v.x - cm4.x) * ci4.x * cmf);
    oc.y = bf16_of(expf(v.y - cm4.y) * ci4.y * cmf);
    oc.z = bf16_of(expf(v.z - cm4.z) * ci4.z * cmf);
    oc.w = bf16_of(expf(v.w - cm4.w) * ci4.w * cmf);
    *(short4*)((short*)row + m4) = o;
    *(short4*)((short*)row + 256 + m4) = oc;
  }
}

// ------ Tpb[ks][b][h][m] = sum_{l in chunk ks} C[h][l] * P_col[l][m] ------
// split-K partials (bf16); M=h, N=m, K=l chunk of 256.
// A: bf16 Cb_hl via stage_g (DMA). B: bf16 P_col transposed scatter.
__global__ __launch_bounds__(256) void k_tgemm(const short* __restrict__ Cb_hl,
                                               const short* __restrict__ PcolS,
                                               short* __restrict__ Tpb) {
  __shared__ short As[4096], Bs[4096];
  XCD_SWZ(4, KSPLIT, NB, bx, by, bz)
  int b = bz;
  int ks = by;
  int h0 = (bx & 1) << 7;
  int m0 = (bx >> 1) << 7;
  GEMM_IDS
  const short* Ag = Cb_hl + ((size_t)b * NH + h0) * NLC;
  const short* Pb = PcolS + (size_t)b * NLC * 512 + 256 + m0;
  f32x4 acc[4][4] = {};
  int kbeg = ks * (NLC / KSPLIT), kend = kbeg + NLC / KSPLIT;
  int lloc = t >> 3, g2 = lloc >> 3, kin = lloc & 7;
  int mbase = (t & 7) << 4;
  for (int k0 = kbeg; k0 < kend; k0 += 32) {
    __syncthreads();
    stage_g(Ag + k0, NLC, As, t);
    {  // B: bf16 P_col passthrough, transposed into swizzled LDS
      const short* srow = Pb + (size_t)(k0 + lloc) * 512;
      short8 x0 = *(const short8*)&srow[mbase];
      short8 x1 = *(const short8*)&srow[mbase + 8];
#pragma unroll
      for (int j = 0; j < 8; ++j) {
        int R = mbase + j;
        int byteoff =
            (R << 6) + (((g2 ^ ((R >> 1) & 3)) & 3) << 4) + (kin << 1);
        *(short*)((char*)Bs + byteoff) = x0[j];
      }
#pragma unroll
      for (int j = 0; j < 8; ++j) {
        int R = mbase + 8 + j;
        int byteoff =
            (R << 6) + (((g2 ^ ((R >> 1) & 3)) & 3) << 4) + (kin << 1);
        *(short*)((char*)Bs + byteoff) = x1[j];
      }
    }
    __syncthreads();
    MFMA_STEP(As, Bs)
  }
  short* dst = Tpb + ((size_t)ks * NB + b) * NH * NLQ;
#pragma unroll
  for (int mi = 0; mi < 4; ++mi)
#pragma unroll
    for (int ni = 0; ni < 4; ++ni)
#pragma unroll
      for (int r = 0; r < 4; ++r) {
        int h = h0 + wr + mi * 16 + g * 4 + r;
        int m = m0 + wc + ni * 16 + ln;
        dst[(size_t)h * NLQ + m] = bf16_of(acc[mi][ni][r]);
      }
}

// reduce KSPLIT bf16 partials -> bf16 Tt[b][h][m], 8 elems/thread
__global__ __launch_bounds__(256) void k_tfin(const short* __restrict__ Tpb,
                                              short* __restrict__ Tt) {
  size_t i = ((size_t)blockIdx.x * 256 + threadIdx.x) * 8;
  const size_t stride = (size_t)NB * NH * NLQ;
  short8 x0 = *(const short8*)&Tpb[i];
  short8 x1 = *(const short8*)&Tpb[i + stride];
  short8 x2 = *(const short8*)&Tpb[i + 2 * stride];
  short8 x3 = *(const short8*)&Tpb[i + 3 * stride];
  short8 o;
#pragma unroll
  for (int j = 0; j < 8; ++j)
    o[j] = bf16_of(f_of(x0[j]) + f_of(x1[j]) + f_of(x2[j]) + f_of(x3[j]));
  *(short8*)&Tt[i] = o;
}

// ---- [A | Ct*Bv][l][h] = f(sum_m P_row[l][m] * X[h][m]); 2-phase dbuf.
// nb<2 epilogue ALSO writes CtA_lh = Ct*A so k_out stages it via pure DMA.
__global__ __launch_bounds__(256) void k_abgemm(
    const short* __restrict__ Prow, const short* __restrict__ Qb_hm,
    const short* __restrict__ Tt, const short* __restrict__ Ct_lh,
    short* __restrict__ A_lh, short* __restrict__ CtA_lh,
    short* __restrict__ CtBv_lh) {
  __shared__ short As[2][4096], Bs[2][4096];
  XCD_SWZ(4, NLC / 128, NB, bx, by, bz)
  int b = bz, l0 = by << 7, nb = bx;
  GEMM_IDS
  const short* Ag = Prow + ((size_t)b * NLC + l0) * 512;
  const short* Bbase = (nb < 2)
                           ? Qb_hm + ((size_t)b * NH + nb * 128) * NLQ
                           : Tt + ((size_t)b * NH + (nb - 2) * 128) * NLQ;
  f32x4 acc[4][4] = {};
  stage_g(Ag, 512, As[0], t);
  stage_g(Bbase, NLQ, Bs[0], t);
  __syncthreads();
  int cur = 0;
  for (int kn = 32; kn <= NLQ; kn += 32) {
    if (kn < NLQ) {
      stage_g(Ag + kn, 512, As[cur ^ 1], t);
      stage_g(Bbase + kn, NLQ, Bs[cur ^ 1], t);
    }
    MFMA_STEP(As[cur], Bs[cur])
    __syncthreads();
    cur ^= 1;
  }
  int hbase = (nb & 1) << 7;
  if (nb < 2) {
#pragma unroll
    for (int mi = 0; mi < 4; ++mi)
#pragma unroll
      for (int ni = 0; ni < 4; ++ni)
#pragma unroll
        for (int r = 0; r < 4; ++r) {
          int l = l0 + wr + mi * 16 + g * 4 + r;
          int h = hbase + wc + ni * 16 + ln;
          size_t off = ((size_t)b * NLC + l) * NH + h;
          float a = acc[mi][ni][r];
          A_lh[off] = bf16_of(a);
          CtA_lh[off] = bf16_of(f_of(Ct_lh[off]) * a);
        }
  } else {
#pragma unroll
    for (int mi = 0; mi < 4; ++mi)
#pragma unroll
      for (int ni = 0; ni < 4; ++ni)
#pragma unroll
        for (int r = 0; r < 4; ++r) {
          int l = l0 + wr + mi * 16 + g * 4 + r;
          int h = hbase + wc + ni * 16 + ln;
          size_t off = ((size_t)b * NLC + l) * NH + h;
          CtBv_lh[off] = bf16_of(f_of(Ct_lh[off]) * acc[mi][ni][r]);
        }
  }
}

// -------- out[h][l] = relu(b + sum_f W[h][f]*cat[l][f]); 2-phase dbuf --------
// cat regions along f: [Ct | A | Ct*A | Ct*Bv] -- ALL pure stage_g DMA.
__global__ __launch_bounds__(256) void k_out(
    const short* __restrict__ Wb, const short* __restrict__ Ct_lh,
    const short* __restrict__ A_lh, const short* __restrict__ CtA_lh,
    const short* __restrict__ CtBv_lh, const float* __restrict__ br,
    float* __restrict__ out) {
  __shared__ short As[2][4096], Bs[2][4096];
  XCD_SWZ(NLC / 128, NH / 128, NB, bx, by, bz)
  int b = bz, h0 = by << 7, l0 = bx << 7;
  GEMM_IDS
  const short* Wg = Wb + (size_t)h0 * (4 * NH);
  size_t boff = ((size_t)b * NLC + l0) * NH;
  f32x4 acc[4][4] = {};
  stage_g(Wg, 4 * NH, As[0], t);
  stage_g(Ct_lh + boff, NH, Bs[0], t);  // tile 0 is region 0 (Ct)
  __syncthreads();
  int cur = 0;
  for (int kn = 32; kn <= 4 * NH; kn += 32) {
    bool has = kn < 4 * NH;
    if (has) {
      stage_g(Wg + kn, 4 * NH, As[cur ^ 1], t);
      int regn = kn >> 8, kon = kn & 255;
      const short* base = (regn == 0) ? Ct_lh
                          : (regn == 1) ? A_lh
                          : (regn == 2) ? CtA_lh : CtBv_lh;
      stage_g(base + boff + kon, NH, Bs[cur ^ 1], t);
    }
    MFMA_STEP(As[cur], Bs[cur])
    __syncthreads();
    cur ^= 1;
  }
#pragma unroll
  for (int mi = 0; mi < 4; ++mi)
#pragma unroll
    for (int ni = 0; ni < 4; ++ni) {
      int h = h0 + wr + mi * 16 + g * 4;
      int l = l0 + wc + ni * 16 + ln;
#pragma unroll
      for (int r = 0; r < 4; ++r) {
        float bias = br[h + r];
        out[((size_t)b * NH + h + r) * NLC + l] =
            fmaxf(acc[mi][ni][r] + bias, 0.f);
      }
    }
}

extern "C" void kernel_launch(void* const* d_in, const int* in_sizes, int n_in,
                              void* d_out, int out_size, void* d_ws,
                              size_t ws_size, hipStream_t stream) {
  (void)in_sizes;
  (void)n_in;
  (void)out_size;
  (void)ws_size;
  const float* C = (const float*)d_in[0];
  const float* Q = (const float*)d_in[1];
  const int* cmask = (const int*)d_in[2];
  const int* qmask = (const int*)d_in[3];
  const float* w = (const float*)d_in[4];
  const float* W = (const float*)d_in[5];
  const float* br = (const float*)d_in[6];
  float* out = (float*)d_out;

  char* p = (char*)d_ws;
  float* S = (float*)p;       p += (size_t)NB * NLC * NLQ * 4;   // 33.6 MB
  short* Ct_lh = (short*)p;   p += (size_t)NB * NLC * NH * 2;    // 16.8 MB
  short* A_lh = (short*)p;    p += (size_t)NB * NLC * NH * 2;    // 16.8 MB
  short* CtBv_lh = (short*)p; p += (size_t)NB * NLC * NH * 2;    // 16.8 MB
  short* CtA_lh = (short*)p;  p += (size_t)NB * NLC * NH * 2;    // 16.8 MB
  short* Cb_hl = (short*)p;   p += (size_t)NB * NH * NLC * 2;    // 16.8 MB
  short* Tt = (short*)p;      p += (size_t)NB * NH * NLQ * 2;    // 4.2 MB
  short* Qtw3 = (short*)p;    p += (size_t)NB * NLQ * NH * 2;    // 4.2 MB
  short* Qb_hm = (short*)p;   p += (size_t)NB * NH * NLQ * 2;    // 4.2 MB
  short* Wb = (short*)p;      p += (size_t)NH * 4 * NH * 2;      // 0.5 MB
  float* pmax = (float*)p;    p += (size_t)NB * NLQ * TCH * 4;
  float* psum = (float*)p;    p += (size_t)NB * NLQ * TCH * 4;
  float* s1p = (float*)p;     p += (size_t)4 * NB * NLC * 4;     // 0.5 MB
  float* s2p = (float*)p;     p += (size_t)4 * NB * NLQ * 4;     // 0.13 MB
  // tgemm split-K bf16 partials: reuse A_lh (16.8 MB, dead until abgemm).
  short* Tpb = A_lh;
  // in-place softmax: bf16 P_row at bytes 0..511, P_col at 512..1023 of each
  // 1KB S row (row stride 512 shorts).
  short* Prow = (short*)S;

  k_prep<<<dim3(2048 + 512), dim3(256), 0, stream>>>(
      C, Q, w, W, Ct_lh, Cb_hl, Qtw3, Qb_hm, Wb, s1p, s2p);
  k_sgemm<<<dim3(NLQ / 128, NLC / 128, NB), dim3(256), 0, stream>>>(
      Ct_lh, Qtw3, s1p, s2p, cmask, S, pmax, psum);
  k_rowsoft<<<dim3(NB * NLC / 16), dim3(256), 0, stream>>>(S, qmask, cmask,
                                                           pmax, psum);
  k_tgemm<<<dim3(4, KSPLIT, NB), dim3(256), 0, stream>>>(Cb_hl, Prow, Tpb);
  k_tfin<<<dim3(NB * NH * NLQ / 2048), dim3(256), 0, stream>>>(Tpb, Tt);
  k_abgemm<<<dim3(4, NLC / 128, NB), dim3(256), 0, stream>>>(
      Prow, Qb_hm, Tt, Ct_lh, A_lh, CtA_lh, CtBv_lh);
  k_out<<<dim3(NLC / 128, NH / 128, NB), dim3(256), 0, stream>>>(
      Wb, Ct_lh, A_lh, CtA_lh, CtBv_lh, br, out);
}